// Round 7
// baseline (1853.888 us; speedup 1.0000x reference)
//
#include <hip/hip_runtime.h>

#define DEG 16
#define DD  128
#define KT  10      // template nodes
#define TT  10      // templates
#define MM  17      // m = DEG+1

#if __has_builtin(__builtin_amdgcn_exp2f)
#define FEXP2(x) __builtin_amdgcn_exp2f(x)
#else
#define FEXP2(x) exp2f(x)
#endif

#if __has_builtin(__builtin_amdgcn_rcpf)
#define FRCP(x) __builtin_amdgcn_rcpf(x)
#else
#define FRCP(x) (1.0f / (x))
#endif

#if __has_builtin(__builtin_amdgcn_logf)
#define FLOG2(x) __builtin_amdgcn_logf(x)
#else
#define FLOG2(x) log2f(x)
#endif

// (1/EPS)*log2(e), EPS = 0.5
#define TWO_LOG2E  2.8853900817779268f
// (0.5/EPS)*log2(e) = log2(e)
#define HALF_LOG2E 1.4426950408889634f
#define LN2        0.6931471805599453f

typedef float    v2f __attribute__((ext_vector_type(2)));
typedef _Float16 h2  __attribute__((ext_vector_type(2)));

__device__ __forceinline__ v2f make2(float s) { v2f r; r.x = s; r.y = s; return r; }

// ---- pure-VALU cross-lane add within each 16-lane row ----
template <int CTRL>
__device__ __forceinline__ float dpp_add(float x) {
    union { float f; int i; } a, b;
    a.f = x;
    b.i = __builtin_amdgcn_update_dpp(0, a.i, CTRL, 0xF, 0xF, true);
    return x + b.f;
}
__device__ __forceinline__ float sum16(float t) {
    t = dpp_add<0xB1>(t);   // quad_perm xor 1
    t = dpp_add<0x4E>(t);   // quad_perm xor 2
    t = dpp_add<0x124>(t);  // row_ror:4
    t = dpp_add<0x128>(t);  // row_ror:8
    return t;
}

// 1-wave blocks (no LDS, no barriers): occupancy = floor(512/VGPR) waves/EU
// with no block-granularity loss. (64,4) caps VGPR at 128 -> never spills;
// if allocation lands <=102 HW gives 5 waves/EU.
__global__ __launch_bounds__(64, 4) void ltfgw_kernel(
    const float* __restrict__ x,      // [N,128]
    const int*   __restrict__ ei,     // edge_index[0], [N*DEG]
    const float* __restrict__ tmpl,   // [T,K,K]
    const float* __restrict__ tf,     // [T,K,128]
    float* __restrict__ out,          // [N,T]
    int N)
{
    const int lane = threadIdx.x;      // 0..63
    const int g    = lane >> 4;        // group 0..3
    const int c    = lane & 15;        // template column (active if <10)
    const bool act = (c < KT);
    const int cc   = act ? c : 0;

    const int w = blockIdx.x % TT;     // template
    const int o = blockIdx.x / TT;     // node octet
    int nx = o * 8 + g;                // problem .x node
    int ny = o * 8 + 4 + g;            // problem .y node
    const bool vx = (nx < N), vy = (ny < N);
    if (nx >= N) nx = N - 1;
    if (ny >= N) ny = N - 1;

    const float* ftrow = tf + (size_t)(w * KT + cc) * DD;

    // E_M[j] = exp(-M[j]) per problem, stored f16 (rel err 5e-4 << threshold)
    h2 E_Mh[MM];

    // ---- feature costs, two row-passes to bound live registers ----
    // pass A: rows 0..8 (self + neighbors 0..7)
    {
        int sx[9], sy[9];
        sx[0] = nx; sy[0] = ny;
        {
            int4 e0 = *(const int4*)(ei + (size_t)nx * DEG);
            int4 e1 = *(const int4*)(ei + (size_t)nx * DEG + 4);
            sx[1] = e0.x; sx[2] = e0.y; sx[3] = e0.z; sx[4] = e0.w;
            sx[5] = e1.x; sx[6] = e1.y; sx[7] = e1.z; sx[8] = e1.w;
        }
        {
            int4 e0 = *(const int4*)(ei + (size_t)ny * DEG);
            int4 e1 = *(const int4*)(ei + (size_t)ny * DEG + 4);
            sy[1] = e0.x; sy[2] = e0.y; sy[3] = e0.z; sy[4] = e0.w;
            sy[5] = e1.x; sy[6] = e1.y; sy[7] = e1.z; sy[8] = e1.w;
        }
        v2f acx[9], acy[9];
#pragma unroll
        for (int j = 0; j < 9; ++j) { acx[j] = make2(0.f); acy[j] = make2(0.f); }
#pragma unroll 2
        for (int kk = 0; kk < DD; kk += 4) {
            float4 f4 = *(const float4*)(ftrow + kk);
            v2f f01; f01.x = f4.x; f01.y = f4.y;
            v2f f23; f23.x = f4.z; f23.y = f4.w;
#pragma unroll
            for (int j = 0; j < 9; ++j) {
                float4 a = *(const float4*)(x + (size_t)sx[j] * DD + kk);
                v2f a01; a01.x = a.x; a01.y = a.y;
                v2f a23; a23.x = a.z; a23.y = a.w;
                v2f d0 = a01 - f01; acx[j] += d0 * d0;
                v2f d1 = a23 - f23; acx[j] += d1 * d1;
                float4 b = *(const float4*)(x + (size_t)sy[j] * DD + kk);
                v2f b01; b01.x = b.x; b01.y = b.y;
                v2f b23; b23.x = b.z; b23.y = b.w;
                v2f e0 = b01 - f01; acy[j] += e0 * e0;
                v2f e1 = b23 - f23; acy[j] += e1 * e1;
            }
        }
#pragma unroll
        for (int j = 0; j < 9; ++j) {
            float Mx = (acx[j].x + acx[j].y) * (1.f / DD);
            float My = (acy[j].x + acy[j].y) * (1.f / DD);
            v2f ev; ev.x = FEXP2(-HALF_LOG2E * Mx); ev.y = FEXP2(-HALF_LOG2E * My);
            E_Mh[j] = __builtin_convertvector(ev, h2);
        }
    }
    // pass B: rows 9..16 (neighbors 8..15)
    {
        int sx[8], sy[8];
        {
            int4 e0 = *(const int4*)(ei + (size_t)nx * DEG + 8);
            int4 e1 = *(const int4*)(ei + (size_t)nx * DEG + 12);
            sx[0] = e0.x; sx[1] = e0.y; sx[2] = e0.z; sx[3] = e0.w;
            sx[4] = e1.x; sx[5] = e1.y; sx[6] = e1.z; sx[7] = e1.w;
        }
        {
            int4 e0 = *(const int4*)(ei + (size_t)ny * DEG + 8);
            int4 e1 = *(const int4*)(ei + (size_t)ny * DEG + 12);
            sy[0] = e0.x; sy[1] = e0.y; sy[2] = e0.z; sy[3] = e0.w;
            sy[4] = e1.x; sy[5] = e1.y; sy[6] = e1.z; sy[7] = e1.w;
        }
        v2f acx[8], acy[8];
#pragma unroll
        for (int j = 0; j < 8; ++j) { acx[j] = make2(0.f); acy[j] = make2(0.f); }
#pragma unroll 2
        for (int kk = 0; kk < DD; kk += 4) {
            float4 f4 = *(const float4*)(ftrow + kk);
            v2f f01; f01.x = f4.x; f01.y = f4.y;
            v2f f23; f23.x = f4.z; f23.y = f4.w;
#pragma unroll
            for (int j = 0; j < 8; ++j) {
                float4 a = *(const float4*)(x + (size_t)sx[j] * DD + kk);
                v2f a01; a01.x = a.x; a01.y = a.y;
                v2f a23; a23.x = a.z; a23.y = a.w;
                v2f d0 = a01 - f01; acx[j] += d0 * d0;
                v2f d1 = a23 - f23; acx[j] += d1 * d1;
                float4 b = *(const float4*)(x + (size_t)sy[j] * DD + kk);
                v2f b01; b01.x = b.x; b01.y = b.y;
                v2f b23; b23.x = b.z; b23.y = b.w;
                v2f e0 = b01 - f01; acy[j] += e0 * e0;
                v2f e1 = b23 - f23; acy[j] += e1 * e1;
            }
        }
#pragma unroll
        for (int j = 0; j < 8; ++j) {
            float Mx = (acx[j].x + acx[j].y) * (1.f / DD);
            float My = (acy[j].x + acy[j].y) * (1.f / DD);
            v2f ev; ev.x = FEXP2(-HALF_LOG2E * Mx); ev.y = FEXP2(-HALF_LOG2E * My);
            E_Mh[9 + j] = __builtin_convertvector(ev, h2);
        }
    }

    // ---- ct2q = (Ct^2 @ q)[c]
    float ct2q = 0.f;
#pragma unroll
    for (int jj = 0; jj < KT; ++jj) {
        float ctj = tmpl[(w * KT + cc) * KT + jj];
        ct2q = fmaf(ctj, ctj, ct2q);
    }
    ct2q *= (1.f / KT);

    // ---- scaled-domain proximal Sinkhorn, two problems in v2f lanes.
    // Invariant: Tp[j][c] = eK[j]*u[j]*vv; after v-step colsum == qw == 0.1.
    const int gbase = lane & ~15;

    v2f eK[MM], u[MM];
    v2f vv = make2(1.f);
    const float einit = act ? (1.f / (MM * KT)) : 0.f;
#pragma unroll
    for (int j = 0; j < MM; ++j) { eK[j] = make2(einit); u[j] = make2(1.f); }

    v2f obj = make2(0.f);

#define SINK_ITER(NEWTON)                                                   \
    {                                                                       \
        v2f cacc = make2(0.f);                                              \
        _Pragma("unroll")                                                   \
        for (int j = 0; j < MM; ++j) {                                      \
            v2f prod = eK[j] * v2;                                          \
            v2f t; t.x = sum16(prod.x); t.y = sum16(prod.y);                \
            if (NEWTON) {                                                   \
                v2f corr = 2.0f - t * u[j];                                 \
                corr = __builtin_elementwise_max(corr, make2(0.0625f));     \
                u[j] = u[j] * corr;                                         \
            } else {                                                        \
                u[j].x = FRCP(t.x); u[j].y = FRCP(t.y);                     \
            }                                                               \
            cacc += eK[j] * u[j];                                           \
        }                                                                   \
        v2.x = act ? 1.7f * FRCP(cacc.x) : 0.f;                             \
        v2.y = act ? 1.7f * FRCP(cacc.y) : 0.f;                             \
    }

#pragma unroll 1
    for (int outer = 0; outer <= 5; ++outer) {
        v2f t0 = eK[0] * u[0] * vv;    // Tp row 0, this column
        v2f s  = 0.1f - t0;            // colsum == qw exactly

        // (Ci@Tp@Ct^T): row0 -> Ct.s ; rows>=1 -> Ct.Tp[0,:]
        v2f Cs = make2(0.f), C0 = make2(0.f);
#pragma unroll
        for (int jj = 0; jj < KT; ++jj) {
            float ctj = tmpl[(w * KT + cc) * KT + jj];
            Cs.x = fmaf(ctj, __shfl(s.x,  gbase + jj, 64), Cs.x);
            Cs.y = fmaf(ctj, __shfl(s.y,  gbase + jj, 64), Cs.y);
            C0.x = fmaf(ctj, __shfl(t0.x, gbase + jj, 64), C0.x);
            C0.y = fmaf(ctj, __shfl(t0.y, gbase + jj, 64), C0.y);
        }

        v2f gw0 = ((16.f / 17.f) + ct2q) - 2.f * Cs;   // row 0
        v2f gw1 = ((1.f / 17.f)  + ct2q) - 2.f * C0;   // rows 1..16

        if (outer == 5) {
            v2f ob = make2(0.f);
#pragma unroll
            for (int j = 0; j < MM; ++j) {
                v2f em = __builtin_convertvector(E_Mh[j], v2f);
                v2f Mc; Mc.x = -LN2 * FLOG2(em.x); Mc.y = -LN2 * FLOG2(em.y);
                v2f Tpj = eK[j] * u[j] * vv;
                v2f gw  = (j == 0) ? gw0 : gw1;
                ob += Tpj * (0.5f * Mc + 0.5f * gw);
            }
            obj = ob;
            break;
        }

        // mirror step: eK <- (eK*u*vv) * E_M * exp(-gw/EPS)
        v2f G0, G1;
        G0.x = FEXP2(-TWO_LOG2E * gw0.x); G0.y = FEXP2(-TWO_LOG2E * gw0.y);
        G1.x = FEXP2(-TWO_LOG2E * gw1.x); G1.y = FEXP2(-TWO_LOG2E * gw1.y);
        v2f f0 = vv * G0, f1 = vv * G1;
        eK[0] = eK[0] * u[0] * __builtin_convertvector(E_Mh[0], v2f) * f0;
#pragma unroll
        for (int j = 1; j < MM; ++j)
            eK[j] = eK[j] * u[j] * __builtin_convertvector(E_Mh[j], v2f) * f1;

        // 10 Sinkhorn iterations: 2 exact-rcp seeds, 8 Newton-refined
        v2f v2 = make2(1.f);
        SINK_ITER(0)
        SINK_ITER(0)
#pragma unroll 1
        for (int it = 2; it < 10; ++it) SINK_ITER(1)

        vv = (1.f / MM) * v2;
    }

    // reduce over the 16-lane group (inactive lanes contribute exact 0)
    obj.x = sum16(obj.x);
    obj.y = sum16(obj.y);

    if (act && c == 0) {
        if (vx) out[nx * TT + w] = obj.x;
        if (vy) out[ny * TT + w] = obj.y;
    }
}

extern "C" void kernel_launch(void* const* d_in, const int* in_sizes, int n_in,
                              void* d_out, int out_size, void* d_ws, size_t ws_size,
                              hipStream_t stream) {
    const float* x    = (const float*)d_in[0];
    const int*   ei   = (const int*)d_in[1];
    const float* tmpl = (const float*)d_in[2];
    const float* tf   = (const float*)d_in[3];
    float* out = (float*)d_out;
    int N = in_sizes[0] / DD;
    int octets = (N + 7) / 8;
    hipLaunchKernelGGL(ltfgw_kernel, dim3(octets * TT), dim3(64), 0, stream,
                       x, ei, tmpl, tf, out, N);
}

// Round 8
// 1423.351 us; speedup vs baseline: 1.3025x; 1.3025x over previous
//
#include <hip/hip_runtime.h>

#define DEG 16
#define DD  128
#define KT  10      // template nodes
#define TT  10      // templates
#define MM  17      // m = DEG+1
#define NR  9       // rows per half-lane (h1: 8 real + 1 inert dummy)
#define THREADS 256 // 4 waves/block, no LDS, no barriers

#if __has_builtin(__builtin_amdgcn_exp2f)
#define FEXP2(x) __builtin_amdgcn_exp2f(x)
#else
#define FEXP2(x) exp2f(x)
#endif

#if __has_builtin(__builtin_amdgcn_rcpf)
#define FRCP(x) __builtin_amdgcn_rcpf(x)
#else
#define FRCP(x) (1.0f / (x))
#endif

#if __has_builtin(__builtin_amdgcn_logf)
#define FLOG2(x) __builtin_amdgcn_logf(x)
#else
#define FLOG2(x) log2f(x)
#endif

// (1/EPS)*log2(e), EPS = 0.5
#define TWO_LOG2E  2.8853900817779268f
// (0.5/EPS)*log2(e) = log2(e)
#define HALF_LOG2E 1.4426950408889634f
#define LN2        0.6931471805599453f

typedef float v2f __attribute__((ext_vector_type(2)));
__device__ __forceinline__ v2f make2(float s) { v2f r; r.x = s; r.y = s; return r; }

// ---- pure-VALU cross-lane add within each 16-lane group ----
template <int CTRL>
__device__ __forceinline__ float dpp_add(float x) {
    union { float f; int i; } a, b;
    a.f = x;
    b.i = __builtin_amdgcn_update_dpp(0, a.i, CTRL, 0xF, 0xF, true);
    return x + b.f;
}
__device__ __forceinline__ float sum16(float t) {
    t = dpp_add<0xB1>(t);   // quad_perm xor 1
    t = dpp_add<0x4E>(t);   // quad_perm xor 2
    t = dpp_add<0x124>(t);  // row_ror:4
    t = dpp_add<0x128>(t);  // row_ror:8
    return t;
}

// Row-split layout: each problem (node,template) occupies 32 lanes =
// 2 x 16-lane groups. Within a group, lane c owns template-column c;
// group h owns rows h==0 ? {0..8} : {9..16,+dummy}. Per-lane Sinkhorn
// state is 27 floats (9 rows) -> whole kernel fits under 64 VGPRs ->
// 8 waves/SIMD with 1-wave granularity (no LDS, no barriers).
__global__ __launch_bounds__(THREADS, 4) void ltfgw_kernel(
    const float* __restrict__ x,      // [N,128]
    const int*   __restrict__ ei,     // edge_index[0], [N*DEG]
    const float* __restrict__ tmpl,   // [T,K,K]
    const float* __restrict__ tf,     // [T,K,128]
    float* __restrict__ out,          // [N,T]
    int N)
{
    const int lane = threadIdx.x & 63;
    const int wid  = threadIdx.x >> 6;     // wave in block
    const int c    = lane & 15;            // template column (active if <10)
    const int h    = (lane >> 4) & 1;      // row-half
    const int pr   = lane >> 5;            // problem slot in wave (0/1)
    const bool act = (c < KT);
    const int cc   = act ? c : 0;

    // problem id: consecutive pids share the node (x rows stay L1/L2-hot)
    long pid  = ((long)blockIdx.x * 4 + wid) * 2 + pr;
    long npid = (long)N * TT;
    const bool valid = (pid < npid);
    if (!valid) pid = 0;
    const int node = (int)(pid / TT);
    const int w    = (int)(pid - (long)node * TT);

    // ---- rows for this half
    int src[NR];
    if (h == 0) {
        src[0] = node;
        int4 e0 = *(const int4*)(ei + (size_t)node * DEG);
        int4 e1 = *(const int4*)(ei + (size_t)node * DEG + 4);
        src[1] = e0.x; src[2] = e0.y; src[3] = e0.z; src[4] = e0.w;
        src[5] = e1.x; src[6] = e1.y; src[7] = e1.z; src[8] = e1.w;
    } else {
        int4 e0 = *(const int4*)(ei + (size_t)node * DEG + 8);
        int4 e1 = *(const int4*)(ei + (size_t)node * DEG + 12);
        src[0] = e0.x; src[1] = e0.y; src[2] = e0.z; src[3] = e0.w;
        src[4] = e1.x; src[5] = e1.y; src[6] = e1.z; src[7] = e1.w;
        src[8] = e0.x;   // dummy (result overwritten / kept inert)
    }

    // ---- feature costs: M[j] = mean((Fi_row - Ft_col)^2)
    const float* ftrow = tf + (size_t)(w * KT + cc) * DD;
    v2f acc2[NR];
#pragma unroll
    for (int j = 0; j < NR; ++j) acc2[j] = make2(0.f);
#pragma unroll 4
    for (int kk = 0; kk < DD; kk += 4) {
        float4 f4 = *(const float4*)(ftrow + kk);
        v2f f01; f01.x = f4.x; f01.y = f4.y;
        v2f f23; f23.x = f4.z; f23.y = f4.w;
#pragma unroll
        for (int j = 0; j < NR; ++j) {
            float4 a = *(const float4*)(x + (size_t)src[j] * DD + kk);
            v2f a01; a01.x = a.x; a01.y = a.y;
            v2f a23; a23.x = a.z; a23.y = a.w;
            v2f d0 = a01 - f01; acc2[j] += d0 * d0;
            v2f d1 = a23 - f23; acc2[j] += d1 * d1;
        }
    }
    float E_M[NR];
#pragma unroll
    for (int j = 0; j < NR; ++j) {
        float Mj = (acc2[j].x + acc2[j].y) * (1.f / DD);
        E_M[j] = FEXP2(-HALF_LOG2E * Mj);
    }
    if (h == 1) E_M[8] = 1.f;              // dummy row: Mc = 0

    // ---- ct2q = (Ct^2 @ q)[c]
    const float* ctp = tmpl + (size_t)(w * KT + cc) * KT;
    float ct2q = 0.f;
#pragma unroll
    for (int jj = 0; jj < KT; ++jj) ct2q = fmaf(ctp[jj], ctp[jj], ct2q);
    ct2q *= (1.f / KT);

    // ---- scaled-domain proximal Sinkhorn
    const int g32 = lane & ~31;            // problem's lane-group base
    const float bias8 = (h == 1) ? 1.f : 0.f;  // keeps dummy row inert (u=1)

    float eK[NR], u[NR];
    const float einit = act ? (1.f / (MM * KT)) : 0.f;
#pragma unroll
    for (int j = 0; j < NR; ++j) { eK[j] = einit; u[j] = 1.f; }
    if (h == 1) eK[8] = 0.f;               // dummy row
    float vv = 1.f;
    float obj = 0.f;

#define SINK_ITER(NEWTON)                                                   \
    {                                                                       \
        float cacc = 0.f;                                                   \
        _Pragma("unroll")                                                   \
        for (int j = 0; j < NR; ++j) {                                      \
            float t = sum16(eK[j] * v2);                                    \
            if (j == 8) t += bias8;                                         \
            if (NEWTON) {                                                   \
                float corr = fmaxf(fmaf(-t, u[j], 2.f), 0.0625f);           \
                u[j] *= corr;                                               \
            } else {                                                        \
                u[j] = FRCP(t);                                             \
            }                                                               \
            cacc = fmaf(eK[j], u[j], cacc);                                 \
        }                                                                   \
        cacc += __shfl_xor(cacc, 16);                                       \
        v2 = act ? 1.7f * FRCP(cacc) : 0.f;                                 \
    }

#pragma unroll 1
    for (int outer = 0; outer <= 5; ++outer) {
        // Tp row 0 lives in half 0, j==0; colsum == qw == 0.1 exactly.
        float t0l = eK[0] * u[0] * vv;
        float s_l = 0.1f - t0l;

        // (Ci@Tp@Ct^T): row0 -> Ct.s ; rows>=1 -> Ct.Tp[0,:]
        float Cs = 0.f, C0 = 0.f;
#pragma unroll
        for (int jj = 0; jj < KT; ++jj) {
            float ctj = ctp[jj];
            Cs = fmaf(ctj, __shfl(s_l, g32 + jj, 64), Cs);
            C0 = fmaf(ctj, __shfl(t0l, g32 + jj, 64), C0);
        }

        float gw0 = (16.f / 17.f) + ct2q - 2.f * Cs;   // row 0
        float gw1 = (1.f / 17.f)  + ct2q - 2.f * C0;   // rows 1..16

        if (outer == 5) {
            float ob = 0.f;
#pragma unroll
            for (int j = 0; j < NR; ++j) {
                float Mc = -LN2 * FLOG2(E_M[j]);
                float gw = (h == 0 && j == 0) ? gw0 : gw1;
                ob += (eK[j] * u[j] * vv) * (0.5f * Mc + 0.5f * gw);
            }
            obj = ob;
            break;
        }

        // mirror step: eK <- (eK*u*vv) * E_M * exp(-gw/EPS)
        float G0 = FEXP2(-TWO_LOG2E * gw0);
        float G1 = FEXP2(-TWO_LOG2E * gw1);
        float f1 = vv * G1;
        float f0 = (h == 0) ? vv * G0 : f1;
        eK[0] = eK[0] * u[0] * E_M[0] * f0;
#pragma unroll
        for (int j = 1; j < NR; ++j) eK[j] = eK[j] * u[j] * E_M[j] * f1;

        // 10 Sinkhorn iterations: 2 exact-rcp seeds, 8 Newton-refined
        float v2 = 1.f;
        SINK_ITER(0)
        SINK_ITER(0)
#pragma unroll 1
        for (int it = 2; it < 10; ++it) SINK_ITER(1)

        vv = (1.f / MM) * v2;
    }

    // reduce: over 16 columns, then across the two halves
    obj = sum16(obj);
    obj += __shfl_xor(obj, 16);

    if (valid && h == 0 && c == 0) out[pid] = obj;
}

extern "C" void kernel_launch(void* const* d_in, const int* in_sizes, int n_in,
                              void* d_out, int out_size, void* d_ws, size_t ws_size,
                              hipStream_t stream) {
    const float* x    = (const float*)d_in[0];
    const int*   ei   = (const int*)d_in[1];
    const float* tmpl = (const float*)d_in[2];
    const float* tf   = (const float*)d_in[3];
    float* out = (float*)d_out;
    int N = in_sizes[0] / DD;
    long npid = (long)N * TT;                 // 2 problems per wave, 4 waves/block
    int grid = (int)((npid + 7) / 8);
    hipLaunchKernelGGL(ltfgw_kernel, dim3(grid), dim3(THREADS), 0, stream,
                       x, ei, tmpl, tf, out, N);
}